// Round 5
// baseline (5042.859 us; speedup 1.0000x reference)
//
#include <hip/hip_runtime.h>
#include <cstddef>

// B=2 T=512 D=512 V=256 MEM=256 ; M = B*T = 1024
// All inputs fp32 (x is int32); all outputs fp32.
#define F_ELUQK 1
#define F_CAUSAL 2
#define F_DIV 4
#define F_NN 8
#define F_SCALE 16

// ---------- ws layout (float units) ----------
enum : int {
  OFF_SIN = 0,                         // [1024][512]
  OFF_GI = 524288,                     // [1024][1536]
  OFF_COMB = OFF_GI + 1572864,         // [1024][2048]  p_f | intent | l_mem | episodes
  OFF_PS = OFF_COMB + 2097152,         // [1024][512]
  OFF_QKV = OFF_PS + 524288,           // [1024][1536]  q(elu+1) | k(elu+1) | v
  OFF_SCORES = OFF_QKV + 1572864,      // [1024][512]
  OFF_DEN = OFF_SCORES + 524288,       // [1024]
  OFF_TMP = OFF_DEN + 1024,            // [1024][512]
  OFF_ATTN = OFF_TMP + 524288,         // [1024][256]
  OFF_SW = OFF_ATTN + 262144,          // [256][512]
  OFF_RING = OFF_SW + 131072,          // [4][1024]  h_f ring
  OFF_HSB = OFF_RING + 4096,           // [2][1024]  h_s double buffer
  OFF_CTR = OFF_HSB + 2048             // ctr1 @ +0, ctr2 @ +32 (128B apart)
};

__global__ __launch_bounds__(256) void embed_kernel(const float* __restrict__ soma,
                                                    const int* __restrict__ x,
                                                    float* __restrict__ sin_) {
  int g = blockIdx.x * 256 + threadIdx.x;     // < 524288
  int m = g >> 9, d = g & 511;
  sin_[g] = soma[(size_t)x[m] * 512 + d];
}

// ---------- generic tiled GEMM:  C[m, coff+n] = sum_k A[m,k] * B(n,k)  (+epilogue) ----------
__global__ __launch_bounds__(256) void gemm(
    const float* __restrict__ A, int lda, const float* __restrict__ B, int ldb,
    float* __restrict__ C, int ldc, int coff, int K,
    const float* __restrict__ bias, const float* __restrict__ den,
    float scale, int flags, int bBatch) {
  __shared__ float As[16 * 65];
  __shared__ float Bs[16 * 65];
  int tid = threadIdx.x;
  int n0 = blockIdx.x * 64, m0 = blockIdx.y * 64;
  int rowoff = (m0 >> 9) * bBatch;
  int tx = tid & 15, ty = tid >> 4;

  if ((flags & F_CAUSAL) && n0 > ((m0 & 511) + 63)) {
    #pragma unroll
    for (int i = 0; i < 4; ++i)
      #pragma unroll
      for (int j = 0; j < 4; ++j)
        C[(size_t)(m0 + ty * 4 + i) * ldc + coff + n0 + tx * 4 + j] = 0.f;
    return;
  }

  float acc[4][4] = {};
  for (int k0 = 0; k0 < K; k0 += 16) {
    {
      int rr = tid >> 2, c4 = (tid & 3) << 2;
      const float* ap = A + (size_t)(m0 + rr) * lda + (k0 + c4);
      float4 av = *(const float4*)ap;
      As[(c4 + 0) * 65 + rr] = av.x;
      As[(c4 + 1) * 65 + rr] = av.y;
      As[(c4 + 2) * 65 + rr] = av.z;
      As[(c4 + 3) * 65 + rr] = av.w;
    }
    if (!(flags & F_NN)) {
      int rr = tid >> 2, c4 = (tid & 3) << 2;
      const float* bp = B + (size_t)(n0 + rr + rowoff) * ldb + (k0 + c4);
      float4 bv = *(const float4*)bp;
      Bs[(c4 + 0) * 65 + rr] = bv.x; Bs[(c4 + 1) * 65 + rr] = bv.y;
      Bs[(c4 + 2) * 65 + rr] = bv.z; Bs[(c4 + 3) * 65 + rr] = bv.w;
    } else {
      int kk = tid >> 4, n4 = (tid & 15) << 2;
      const float* bp = B + (size_t)(k0 + kk + rowoff) * ldb + (n0 + n4);
      float4 bv = *(const float4*)bp;
      Bs[kk * 65 + n4 + 0] = bv.x; Bs[kk * 65 + n4 + 1] = bv.y;
      Bs[kk * 65 + n4 + 2] = bv.z; Bs[kk * 65 + n4 + 3] = bv.w;
    }
    __syncthreads();
    #pragma unroll
    for (int k = 0; k < 16; ++k) {
      float av[4], bv[4];
      #pragma unroll
      for (int i = 0; i < 4; ++i) av[i] = As[k * 65 + ty * 4 + i];
      #pragma unroll
      for (int j = 0; j < 4; ++j) bv[j] = Bs[k * 65 + tx * 4 + j];
      #pragma unroll
      for (int i = 0; i < 4; ++i)
        #pragma unroll
        for (int j = 0; j < 4; ++j)
          acc[i][j] = fmaf(av[i], bv[j], acc[i][j]);
    }
    __syncthreads();
  }
  #pragma unroll
  for (int i = 0; i < 4; ++i) {
    int m = m0 + ty * 4 + i;
    float dv = (flags & F_DIV) ? (1.0f / (den[m] + 1e-6f)) : 1.0f;
    #pragma unroll
    for (int j = 0; j < 4; ++j) {
      int n = n0 + tx * 4 + j;
      float v = acc[i][j];
      if (bias) v += bias[n];
      if (flags & F_ELUQK) { if (n < 1024) v = (v > 0.f) ? (v + 1.f) : __expf(v); }
      if (flags & F_CAUSAL) { if (n > (m & 511)) v = 0.f; }
      if (flags & F_SCALE) v *= scale;
      if (flags & F_DIV) v *= dv;
      C[(size_t)m * ldc + coff + n] = v;
    }
  }
}

// ---------- fused two-layer pipelined GRU scan ----------
// 128 WGs. WG 0..63 = fast GRU (layer1), WG 64..127 = slow GRU (layer2, lags 1 round).
// Each WG owns 8 hidden units: whh rows {j,j+512,j+1024} in LDS.
// Layer1 publishes h_f into a depth-4 sc1 ring; layer2 computes gi_s on the fly
// (slow_wih rows streamed from global/L2) and keeps h_s in an sc1 double buffer.
// Per-layer counters; relaxed agent spins (no fences -> no L2 invalidation).
__global__ __launch_bounds__(256) void gru2_kernel(
    const float* __restrict__ gi,       // gi_f [1024][1536]
    const float* __restrict__ fwhh, const float* __restrict__ fbhh,
    const float* __restrict__ h0f,
    const float* __restrict__ swih, const float* __restrict__ sbih,
    const float* __restrict__ swhh, const float* __restrict__ sbhh,
    const float* __restrict__ h0s,
    float* __restrict__ pf_out,         // COMB cols [0,512), ld 2048
    float* __restrict__ ps_out,         // PS, ld 512
    float* __restrict__ hfT, float* __restrict__ hsT,
    float* __restrict__ ring,           // [4][1024]
    float* __restrict__ hsbuf,          // [2][1024]
    unsigned int* __restrict__ ctr1, unsigned int* __restrict__ ctr2) {
  __shared__ float wl[24 * 516];
  __shared__ unsigned long long hlq[512];   // recurrent h (own layer)
  __shared__ unsigned long long hfq[512];   // p_f input (layer2 only)
  __shared__ float P[48];                   // gh partials
  __shared__ float Q[48];                   // gi partials (layer2)
  __shared__ float bl[24];
  __shared__ float bi[24];
  float* hl = (float*)hlq;
  float* hf = (float*)hfq;
  unsigned long long* ringq = (unsigned long long*)ring;
  unsigned long long* hsq = (unsigned long long*)hsbuf;
  int tid = threadIdx.x, wg = blockIdx.x;
  bool L1 = wg < 64;
  int j0 = (wg & 63) * 8;
  const float* whh = L1 ? fwhh : swhh;
  const float* bhh = L1 ? fbhh : sbhh;

  for (int q = tid; q < 3072; q += 256) {        // 24*512/4
    int r = q >> 7, c4 = (q & 127) << 2;
    int row = (r >> 3) * 512 + j0 + (r & 7);
    float4 v = *(const float4*)(whh + (size_t)row * 512 + c4);
    wl[r * 516 + c4 + 0] = v.x; wl[r * 516 + c4 + 1] = v.y;
    wl[r * 516 + c4 + 2] = v.z; wl[r * 516 + c4 + 3] = v.w;
  }
  if (tid < 24) {
    bl[tid] = bhh[(tid >> 3) * 512 + j0 + (tid & 7)];
    if (!L1) bi[tid] = sbih[(tid >> 3) * 512 + j0 + (tid & 7)];
  }
  int part = tid & 7, rr = tid >> 3;

  if (L1) {
    for (int t = 0; t < 512; ++t) {
      // throttle: don't overwrite ring slot t&3 (holds h_f(t-4)) until layer2
      // consumed it (layer2 round t-3 done => ctr2 >= 64*(t-3))
      if (tid == 0 && t >= 4) {
        unsigned tgt = 64u * (unsigned)(t - 3);
        while (__hip_atomic_load(ctr2, __ATOMIC_RELAXED, __HIP_MEMORY_SCOPE_AGENT) < tgt)
          __builtin_amdgcn_s_sleep(1);
      }
      float i_r = 0.f, i_z = 0.f, i_n = 0.f;
      if (t == 0) {
        const unsigned long long* h0q = (const unsigned long long*)h0f;
        hlq[tid] = h0q[tid]; hlq[256 + tid] = h0q[256 + tid];
      } else {
        int boff = ((t - 1) & 3) * 512;
        hlq[tid] = __hip_atomic_load(ringq + boff + tid, __ATOMIC_RELAXED, __HIP_MEMORY_SCOPE_AGENT);
        hlq[256 + tid] = __hip_atomic_load(ringq + boff + 256 + tid, __ATOMIC_RELAXED, __HIP_MEMORY_SCOPE_AGENT);
      }
      if (tid < 16) {
        int b = tid >> 3, jl = tid & 7;
        const float* girow = gi + (size_t)(b * 512 + t) * 1536 + j0 + jl;
        i_r = girow[0]; i_z = girow[512]; i_n = girow[1024];
      }
      __syncthreads();
      if (rr < 24) {
        const float* wr = wl + rr * 516;
        float a0 = 0.f, a1 = 0.f;
        #pragma unroll 8
        for (int i = 0; i < 32; ++i) {
          int c = (i << 4) + (part << 1);
          float2 w = *(const float2*)(wr + c);
          float2 ha = *(const float2*)(hl + c);
          float2 hb = *(const float2*)(hl + 512 + c);
          a0 += w.x * ha.x + w.y * ha.y;
          a1 += w.x * hb.x + w.y * hb.y;
        }
        a0 += __shfl_xor(a0, 1); a0 += __shfl_xor(a0, 2); a0 += __shfl_xor(a0, 4);
        a1 += __shfl_xor(a1, 1); a1 += __shfl_xor(a1, 2); a1 += __shfl_xor(a1, 4);
        if (part == 0) { P[rr] = a0; P[24 + rr] = a1; }
      }
      __syncthreads();
      if (tid < 16) {
        int b = tid >> 3, jl = tid & 7, j = j0 + jl;
        float gh_r = P[b * 24 + jl] + bl[jl];
        float gh_z = P[b * 24 + 8 + jl] + bl[8 + jl];
        float gh_n = P[b * 24 + 16 + jl] + bl[16 + jl];
        float hold = hl[b * 512 + j];
        float rg = 1.0f / (1.0f + __expf(-(i_r + gh_r)));
        float zg = 1.0f / (1.0f + __expf(-(i_z + gh_z)));
        float ng = tanhf(i_n + rg * gh_n);
        float hnew = (1.0f - zg) * ng + zg * hold;
        __hip_atomic_store(ring + (size_t)(t & 3) * 1024 + b * 512 + j, hnew,
                           __ATOMIC_RELAXED, __HIP_MEMORY_SCOPE_AGENT);
        pf_out[(size_t)(b * 512 + t) * 2048 + j] = hnew;
        if (t == 511) hfT[b * 512 + j] = hnew;
      }
      __syncthreads();   // drains vmcnt: sc1 stores globally visible
      if (tid == 0) {
        __hip_atomic_fetch_add(ctr1, 1u, __ATOMIC_RELEASE, __HIP_MEMORY_SCOPE_AGENT);
        if (t < 511) {
          unsigned target = 64u * (unsigned)(t + 1);
          while (__hip_atomic_load(ctr1, __ATOMIC_RELAXED, __HIP_MEMORY_SCOPE_AGENT) < target)
            __builtin_amdgcn_s_sleep(1);
        }
      }
      __syncthreads();
    }
  } else {
    for (int t2 = 0; t2 < 512; ++t2) {
      // wait: layer1 finished round t2 => p_f(t2) in ring[t2&3]
      if (tid == 0) {
        unsigned tgt = 64u * (unsigned)(t2 + 1);
        while (__hip_atomic_load(ctr1, __ATOMIC_RELAXED, __HIP_MEMORY_SCOPE_AGENT) < tgt)
          __builtin_amdgcn_s_sleep(1);
      }
      __syncthreads();
      if (t2 == 0) {
        const unsigned long long* h0q = (const unsigned long long*)h0s;
        hlq[tid] = h0q[tid]; hlq[256 + tid] = h0q[256 + tid];
      } else {
        int boff = ((t2 - 1) & 1) * 512;
        hlq[tid] = __hip_atomic_load(hsq + boff + tid, __ATOMIC_RELAXED, __HIP_MEMORY_SCOPE_AGENT);
        hlq[256 + tid] = __hip_atomic_load(hsq + boff + 256 + tid, __ATOMIC_RELAXED, __HIP_MEMORY_SCOPE_AGENT);
      }
      {
        int foff = (t2 & 3) * 512;
        hfq[tid] = __hip_atomic_load(ringq + foff + tid, __ATOMIC_RELAXED, __HIP_MEMORY_SCOPE_AGENT);
        hfq[256 + tid] = __hip_atomic_load(ringq + foff + 256 + tid, __ATOMIC_RELAXED, __HIP_MEMORY_SCOPE_AGENT);
      }
      __syncthreads();
      if (rr < 24) {
        // gh = whh (LDS) . h_s
        const float* wr = wl + rr * 516;
        float a0 = 0.f, a1 = 0.f;
        #pragma unroll 8
        for (int i = 0; i < 32; ++i) {
          int c = (i << 4) + (part << 1);
          float2 w = *(const float2*)(wr + c);
          float2 ha = *(const float2*)(hl + c);
          float2 hb = *(const float2*)(hl + 512 + c);
          a0 += w.x * ha.x + w.y * ha.y;
          a1 += w.x * hb.x + w.y * hb.y;
        }
        a0 += __shfl_xor(a0, 1); a0 += __shfl_xor(a0, 2); a0 += __shfl_xor(a0, 4);
        a1 += __shfl_xor(a1, 1); a1 += __shfl_xor(a1, 2); a1 += __shfl_xor(a1, 4);
        if (part == 0) { P[rr] = a0; P[24 + rr] = a1; }
        // gi = swih (global/L2 stream) . p_f
        int wrow = (rr >> 3) * 512 + j0 + (rr & 7);
        const float* wp = swih + (size_t)wrow * 512 + (part << 6);
        const float* h0p = hf + (part << 6);
        const float* h1p = hf + 512 + (part << 6);
        float b0 = 0.f, b1 = 0.f;
        #pragma unroll
        for (int i = 0; i < 16; ++i) {
          float4 w4 = *(const float4*)(wp + (i << 2));
          float4 c0 = *(const float4*)(h0p + (i << 2));
          float4 c1 = *(const float4*)(h1p + (i << 2));
          b0 += w4.x * c0.x + w4.y * c0.y + w4.z * c0.z + w4.w * c0.w;
          b1 += w4.x * c1.x + w4.y * c1.y + w4.z * c1.z + w4.w * c1.w;
        }
        b0 += __shfl_xor(b0, 1); b0 += __shfl_xor(b0, 2); b0 += __shfl_xor(b0, 4);
        b1 += __shfl_xor(b1, 1); b1 += __shfl_xor(b1, 2); b1 += __shfl_xor(b1, 4);
        if (part == 0) { Q[rr] = b0; Q[24 + rr] = b1; }
      }
      __syncthreads();
      if (tid < 16) {
        int b = tid >> 3, jl = tid & 7, j = j0 + jl;
        float i_r = Q[b * 24 + jl] + bi[jl];
        float i_z = Q[b * 24 + 8 + jl] + bi[8 + jl];
        float i_n = Q[b * 24 + 16 + jl] + bi[16 + jl];
        float gh_r = P[b * 24 + jl] + bl[jl];
        float gh_z = P[b * 24 + 8 + jl] + bl[8 + jl];
        float gh_n = P[b * 24 + 16 + jl] + bl[16 + jl];
        float hold = hl[b * 512 + j];
        float rg = 1.0f / (1.0f + __expf(-(i_r + gh_r)));
        float zg = 1.0f / (1.0f + __expf(-(i_z + gh_z)));
        float ng = tanhf(i_n + rg * gh_n);
        float hnew = (1.0f - zg) * ng + zg * hold;
        __hip_atomic_store(hsbuf + (size_t)(t2 & 1) * 1024 + b * 512 + j, hnew,
                           __ATOMIC_RELAXED, __HIP_MEMORY_SCOPE_AGENT);
        ps_out[(size_t)(b * 512 + t2) * 512 + j] = hnew;
        if (t2 == 511) hsT[b * 512 + j] = hnew;
      }
      __syncthreads();
      if (tid == 0) {
        __hip_atomic_fetch_add(ctr2, 1u, __ATOMIC_RELEASE, __HIP_MEMORY_SCOPE_AGENT);
        if (t2 < 511) {
          unsigned target = 64u * (unsigned)(t2 + 1);
          while (__hip_atomic_load(ctr2, __ATOMIC_RELAXED, __HIP_MEMORY_SCOPE_AGENT) < target)
            __builtin_amdgcn_s_sleep(1);
        }
      }
      __syncthreads();
    }
  }
}

// ---------- row reductions ----------
__global__ __launch_bounds__(256) void rowsum_kernel(const float* __restrict__ S,
                                                     float* __restrict__ den) {
  int m = blockIdx.x, tid = threadIdx.x;
  float s = S[(size_t)m * 512 + tid] + S[(size_t)m * 512 + 256 + tid];
  #pragma unroll
  for (int off = 32; off > 0; off >>= 1) s += __shfl_down(s, off);
  __shared__ float r4[4];
  if ((tid & 63) == 0) r4[tid >> 6] = s;
  __syncthreads();
  if (tid == 0) den[m] = r4[0] + r4[1] + r4[2] + r4[3];
}

__global__ __launch_bounds__(256) void softmax_kernel(float* __restrict__ a) {
  int m = blockIdx.x, tid = threadIdx.x;
  float v = a[(size_t)m * 256 + tid];
  float mx = v;
  #pragma unroll
  for (int off = 32; off > 0; off >>= 1) mx = fmaxf(mx, __shfl_down(mx, off));
  __shared__ float r4[4];
  __shared__ float s4[4];
  if ((tid & 63) == 0) r4[tid >> 6] = mx;
  __syncthreads();
  mx = fmaxf(fmaxf(r4[0], r4[1]), fmaxf(r4[2], r4[3]));
  float e = __expf(v - mx);
  float s = e;
  #pragma unroll
  for (int off = 32; off > 0; off >>= 1) s += __shfl_down(s, off);
  if ((tid & 63) == 0) s4[tid >> 6] = s;
  __syncthreads();
  s = s4[0] + s4[1] + s4[2] + s4[3];
  a[(size_t)m * 256 + tid] = e / s;
}

__global__ __launch_bounds__(256) void ln_kernel(
    const float* __restrict__ src, float* __restrict__ dst, int ldd, int dcoff,
    const float* __restrict__ gv, const float* __restrict__ bv, int tanhFirst) {
  int m = blockIdx.x, tid = threadIdx.x;
  float x0 = src[(size_t)m * 512 + tid];
  float x1 = src[(size_t)m * 512 + 256 + tid];
  if (tanhFirst) { x0 = tanhf(x0); x1 = tanhf(x1); }
  float s = x0 + x1, ss = x0 * x0 + x1 * x1;
  #pragma unroll
  for (int off = 32; off > 0; off >>= 1) { s += __shfl_down(s, off); ss += __shfl_down(ss, off); }
  __shared__ float rs[4], rss[4];
  if ((tid & 63) == 0) { rs[tid >> 6] = s; rss[tid >> 6] = ss; }
  __syncthreads();
  float st = rs[0] + rs[1] + rs[2] + rs[3];
  float sst = rss[0] + rss[1] + rss[2] + rss[3];
  float mean = st * (1.0f / 512.0f);
  float var = sst * (1.0f / 512.0f) - mean * mean;
  float inv = rsqrtf(var + 1e-5f);
  float y0 = (x0 - mean) * inv * gv[tid] + bv[tid];
  float y1 = (x1 - mean) * inv * gv[256 + tid] + bv[256 + tid];
  if (!tanhFirst) { y0 = tanhf(y0); y1 = tanhf(y1); }
  dst[(size_t)m * ldd + dcoff + tid] = y0;
  dst[(size_t)m * ldd + dcoff + 256 + tid] = y1;
}

__global__ __launch_bounds__(256) void swnorm_kernel(const float* __restrict__ soma,
                                                     float* __restrict__ sw) {
  int r = blockIdx.x, tid = threadIdx.x;
  float x0 = soma[(size_t)r * 512 + tid];
  float x1 = soma[(size_t)r * 512 + 256 + tid];
  float ss = x0 * x0 + x1 * x1;
  #pragma unroll
  for (int off = 32; off > 0; off >>= 1) ss += __shfl_down(ss, off);
  __shared__ float r4[4];
  if ((tid & 63) == 0) r4[tid >> 6] = ss;
  __syncthreads();
  float norm = sqrtf(r4[0] + r4[1] + r4[2] + r4[3]);
  norm = fmaxf(norm, 1e-12f);
  float inv = 1.0f / norm;
  sw[(size_t)r * 512 + tid] = x0 * inv;
  sw[(size_t)r * 512 + 256 + tid] = x1 * inv;
}

// ---------- host ----------
extern "C" void kernel_launch(void* const* d_in, const int* in_sizes, int n_in,
                              void* d_out, int out_size, void* d_ws, size_t ws_size,
                              hipStream_t stream) {
  (void)in_sizes; (void)n_in; (void)out_size; (void)ws_size;
  float* W = (float*)d_ws;
  float* outf = (float*)d_out;
  // out layout (floats): logits[262144] | thought[524288] | hf1[1024] | hs1[1024]
  const int* x = (const int*)d_in[0];
  const float* soma = (const float*)d_in[3];

  hipMemsetAsync((char*)d_ws + (size_t)OFF_CTR * 4, 0, 256, stream);

  embed_kernel<<<2048, 256, 0, stream>>>(soma, x, W + OFF_SIN);

  // gi_f = s_in @ fast_wih^T + fast_bih
  gemm<<<dim3(24, 16), 256, 0, stream>>>(W + OFF_SIN, 512, (const float*)d_in[4], 512,
      W + OFF_GI, 1536, 0, 512, (const float*)d_in[6], nullptr, 1.f, 0, 0);

  // fused GRU1+GRU2 -> p_f (COMB cols [0,512)), p_s (PS), hf1/hs1 -> out
  gru2_kernel<<<128, 256, 0, stream>>>(W + OFF_GI,
      (const float*)d_in[5], (const float*)d_in[7], (const float*)d_in[1],
      (const float*)d_in[8], (const float*)d_in[10],
      (const float*)d_in[9], (const float*)d_in[11], (const float*)d_in[2],
      W + OFF_COMB, W + OFF_PS, outf + 786432, outf + 787456,
      W + OFF_RING, W + OFF_HSB,
      (unsigned int*)(W + OFF_CTR), (unsigned int*)(W + OFF_CTR) + 32);

  // qkv = p_s @ qkv_w^T + b ; elu+1 on q,k
  gemm<<<dim3(24, 16), 256, 0, stream>>>(W + OFF_PS, 512, (const float*)d_in[12], 512,
      W + OFF_QKV, 1536, 0, 512, (const float*)d_in[13], nullptr, 1.f, F_ELUQK, 0);

  // scores = causal(q k^T) per batch
  gemm<<<dim3(8, 16), 256, 0, stream>>>(W + OFF_QKV, 1536, W + OFF_QKV + 512, 1536,
      W + OFF_SCORES, 512, 0, 512, nullptr, nullptr, 1.f, F_CAUSAL, 512);

  rowsum_kernel<<<1024, 256, 0, stream>>>(W + OFF_SCORES, W + OFF_DEN);

  // l_mem = (scores @ v) / (den + 1e-6) -> combined cols [1024,1536)
  gemm<<<dim3(8, 16), 256, 0, stream>>>(W + OFF_SCORES, 512, W + OFF_QKV + 1024, 1536,
      W + OFF_COMB, 2048, 1024, 512, nullptr, W + OFF_DEN, 1.f, F_NN | F_DIV, 512);

  // intent = tanh(LN(p_s @ gate_w^T + gate_b)) -> combined cols [512,1024)
  gemm<<<dim3(8, 16), 256, 0, stream>>>(W + OFF_PS, 512, (const float*)d_in[14], 512,
      W + OFF_TMP, 512, 0, 512, (const float*)d_in[15], nullptr, 1.f, 0, 0);
  ln_kernel<<<1024, 256, 0, stream>>>(W + OFF_TMP, W + OFF_COMB, 2048, 512,
      (const float*)d_in[16], (const float*)d_in[17], 0);

  // hippocampus -> combined cols [1536,2048)
  gemm<<<dim3(8, 16), 256, 0, stream>>>(W + OFF_PS, 512, (const float*)d_in[19], 512,
      W + OFF_TMP, 512, 0, 512, (const float*)d_in[20], nullptr, 1.f, 0, 0);
  gemm<<<dim3(4, 16), 256, 0, stream>>>(W + OFF_TMP, 512, (const float*)d_in[18], 512,
      W + OFF_ATTN, 256, 0, 512, nullptr, nullptr, 0.04419417382415922f, F_SCALE, 0);
  softmax_kernel<<<1024, 256, 0, stream>>>(W + OFF_ATTN);
  gemm<<<dim3(8, 16), 256, 0, stream>>>(W + OFF_ATTN, 256, (const float*)d_in[18], 512,
      W + OFF_COMB, 2048, 1536, 256, nullptr, nullptr, 1.f, F_NN, 0);

  // axon + LN -> thought directly into out (fp32)
  gemm<<<dim3(8, 16), 256, 0, stream>>>(W + OFF_COMB, 2048, (const float*)d_in[21], 2048,
      W + OFF_TMP, 512, 0, 2048, (const float*)d_in[22], nullptr, 1.f, 0, 0);
  ln_kernel<<<1024, 256, 0, stream>>>(W + OFF_TMP, outf + 262144, 512, 0,
      (const float*)d_in[23], (const float*)d_in[24], 1);

  // logits = (thought @ sw^T) * 16 -> out (fp32)
  swnorm_kernel<<<256, 256, 0, stream>>>(soma, W + OFF_SW);
  gemm<<<dim3(4, 16), 256, 0, stream>>>(outf + 262144, 512, W + OFF_SW, 512,
      outf, 256, 0, 512, nullptr, nullptr, 16.f, F_SCALE, 0);
}

// Round 6
// 2612.902 us; speedup vs baseline: 1.9300x; 1.9300x over previous
//
#include <hip/hip_runtime.h>
#include <cstddef>

// B=2 T=512 D=512 V=256 MEM=256 ; M = B*T = 1024
// All inputs fp32 (x is int32); all outputs fp32.
#define F_ELUQK 1
#define F_CAUSAL 2
#define F_DIV 4
#define F_NN 8
#define F_SCALE 16
#define FLAG_STRIDE 32   // u32 units -> 128 B per WG flag line

// ---------- ws layout (float units) ----------
enum : int {
  OFF_SIN = 0,                         // [1024][512]
  OFF_GI = 524288,                     // [1024][1536]
  OFF_COMB = OFF_GI + 1572864,         // [1024][2048]  p_f | intent | l_mem | episodes
  OFF_PS = OFF_COMB + 2097152,         // [1024][512]
  OFF_QKV = OFF_PS + 524288,           // [1024][1536]  q(elu+1) | k(elu+1) | v
  OFF_SCORES = OFF_QKV + 1572864,      // [1024][512]
  OFF_DEN = OFF_SCORES + 524288,       // [1024]
  OFF_TMP = OFF_DEN + 1024,            // [1024][512]
  OFF_ATTN = OFF_TMP + 524288,         // [1024][256]
  OFF_SW = OFF_ATTN + 262144,          // [256][512]
  OFF_RING = OFF_SW + 131072,          // [4][1024]  h_f ring
  OFF_HSB = OFF_RING + 4096,           // [2][1024]  h_s double buffer
  OFF_FLAGS = OFF_HSB + 2048           // flagsA[64*32] | flagsB[64*32]  (16 KB)
};

__global__ __launch_bounds__(256) void embed_kernel(const float* __restrict__ soma,
                                                    const int* __restrict__ x,
                                                    float* __restrict__ sin_) {
  int g = blockIdx.x * 256 + threadIdx.x;     // < 524288
  int m = g >> 9, d = g & 511;
  sin_[g] = soma[(size_t)x[m] * 512 + d];
}

// ---------- generic tiled GEMM:  C[m, coff+n] = sum_k A[m,k] * B(n,k)  (+epilogue) ----------
__global__ __launch_bounds__(256) void gemm(
    const float* __restrict__ A, int lda, const float* __restrict__ B, int ldb,
    float* __restrict__ C, int ldc, int coff, int K,
    const float* __restrict__ bias, const float* __restrict__ den,
    float scale, int flags, int bBatch) {
  __shared__ float As[16 * 65];
  __shared__ float Bs[16 * 65];
  int tid = threadIdx.x;
  int n0 = blockIdx.x * 64, m0 = blockIdx.y * 64;
  int rowoff = (m0 >> 9) * bBatch;
  int tx = tid & 15, ty = tid >> 4;

  if ((flags & F_CAUSAL) && n0 > ((m0 & 511) + 63)) {
    #pragma unroll
    for (int i = 0; i < 4; ++i)
      #pragma unroll
      for (int j = 0; j < 4; ++j)
        C[(size_t)(m0 + ty * 4 + i) * ldc + coff + n0 + tx * 4 + j] = 0.f;
    return;
  }

  float acc[4][4] = {};
  for (int k0 = 0; k0 < K; k0 += 16) {
    {
      int rr = tid >> 2, c4 = (tid & 3) << 2;
      const float* ap = A + (size_t)(m0 + rr) * lda + (k0 + c4);
      float4 av = *(const float4*)ap;
      As[(c4 + 0) * 65 + rr] = av.x;
      As[(c4 + 1) * 65 + rr] = av.y;
      As[(c4 + 2) * 65 + rr] = av.z;
      As[(c4 + 3) * 65 + rr] = av.w;
    }
    if (!(flags & F_NN)) {
      int rr = tid >> 2, c4 = (tid & 3) << 2;
      const float* bp = B + (size_t)(n0 + rr + rowoff) * ldb + (k0 + c4);
      float4 bv = *(const float4*)bp;
      Bs[(c4 + 0) * 65 + rr] = bv.x; Bs[(c4 + 1) * 65 + rr] = bv.y;
      Bs[(c4 + 2) * 65 + rr] = bv.z; Bs[(c4 + 3) * 65 + rr] = bv.w;
    } else {
      int kk = tid >> 4, n4 = (tid & 15) << 2;
      const float* bp = B + (size_t)(k0 + kk + rowoff) * ldb + (n0 + n4);
      float4 bv = *(const float4*)bp;
      Bs[kk * 65 + n4 + 0] = bv.x; Bs[kk * 65 + n4 + 1] = bv.y;
      Bs[kk * 65 + n4 + 2] = bv.z; Bs[kk * 65 + n4 + 3] = bv.w;
    }
    __syncthreads();
    #pragma unroll
    for (int k = 0; k < 16; ++k) {
      float av[4], bv[4];
      #pragma unroll
      for (int i = 0; i < 4; ++i) av[i] = As[k * 65 + ty * 4 + i];
      #pragma unroll
      for (int j = 0; j < 4; ++j) bv[j] = Bs[k * 65 + tx * 4 + j];
      #pragma unroll
      for (int i = 0; i < 4; ++i)
        #pragma unroll
        for (int j = 0; j < 4; ++j)
          acc[i][j] = fmaf(av[i], bv[j], acc[i][j]);
    }
    __syncthreads();
  }
  #pragma unroll
  for (int i = 0; i < 4; ++i) {
    int m = m0 + ty * 4 + i;
    float dv = (flags & F_DIV) ? (1.0f / (den[m] + 1e-6f)) : 1.0f;
    #pragma unroll
    for (int j = 0; j < 4; ++j) {
      int n = n0 + tx * 4 + j;
      float v = acc[i][j];
      if (bias) v += bias[n];
      if (flags & F_ELUQK) { if (n < 1024) v = (v > 0.f) ? (v + 1.f) : __expf(v); }
      if (flags & F_CAUSAL) { if (n > (m & 511)) v = 0.f; }
      if (flags & F_SCALE) v *= scale;
      if (flags & F_DIV) v *= dv;
      C[(size_t)m * ldc + coff + n] = v;
    }
  }
}

// ---------- flag-based device barrier helpers ----------
// Each WG posts its own 128B-strided flag line (parallel LLC stores, no RMW
// serialization). Waiting: lanes 0..63 each spin on one WG's flag; exec-mask
// reconvergence = free 64-way AND. Relaxed agent ops only (no L2 invalidates).
__device__ __forceinline__ void post_flag(unsigned* flags, int w, unsigned v) {
  __hip_atomic_store(flags + (size_t)w * FLAG_STRIDE, v, __ATOMIC_RELAXED,
                     __HIP_MEMORY_SCOPE_AGENT);
}
__device__ __forceinline__ void wait_flags(const unsigned* flags, unsigned target, int tid) {
  if (tid < 64) {
    const unsigned* p = flags + (size_t)tid * FLAG_STRIDE;
    while (__hip_atomic_load(p, __ATOMIC_RELAXED, __HIP_MEMORY_SCOPE_AGENT) < target)
      __builtin_amdgcn_s_sleep(1);
  }
}

// ---------- fused two-layer pipelined GRU scan ----------
// 128 WGs. WG 0..63 = fast GRU (layer1), WG 64..127 = slow GRU (layer2, lags 1).
// Each WG owns 8 hidden units; its 24 whh rows live in LDS; layer2 additionally
// holds its 24 slow_wih rows in REGISTERS (16 float4/lane, interleaved chunks ->
// conflict-free LDS fragment reads). h broadcast via sc1 ring / double buffer.
__global__ __launch_bounds__(256) void gru2_kernel(
    const float* __restrict__ gi,       // gi_f [1024][1536]
    const float* __restrict__ fwhh, const float* __restrict__ fbhh,
    const float* __restrict__ h0f,
    const float* __restrict__ swih, const float* __restrict__ sbih,
    const float* __restrict__ swhh, const float* __restrict__ sbhh,
    const float* __restrict__ h0s,
    float* __restrict__ pf_out,         // COMB cols [0,512), ld 2048
    float* __restrict__ ps_out,         // PS, ld 512
    float* __restrict__ hfT, float* __restrict__ hsT,
    float* __restrict__ ring,           // [4][1024]
    float* __restrict__ hsbuf,          // [2][1024]
    unsigned* __restrict__ flagsA, unsigned* __restrict__ flagsB) {
  __shared__ float wl[24 * 516];
  __shared__ unsigned long long hlq[512];   // recurrent h (own layer)
  __shared__ unsigned long long hfq[512];   // p_f input (layer2 only)
  __shared__ float P[48];
  __shared__ float Q[48];
  __shared__ float bl[24];
  __shared__ float bi[24];
  float* hl = (float*)hlq;
  float* hf = (float*)hfq;
  unsigned long long* ringq = (unsigned long long*)ring;
  unsigned long long* hsq = (unsigned long long*)hsbuf;
  int tid = threadIdx.x, wg = blockIdx.x;
  bool L1 = wg < 64;
  int j0 = (wg & 63) * 8;
  const float* whh = L1 ? fwhh : swhh;
  const float* bhh = L1 ? fbhh : sbhh;

  for (int q = tid; q < 3072; q += 256) {        // 24*512/4
    int r = q >> 7, c4 = (q & 127) << 2;
    int row = (r >> 3) * 512 + j0 + (r & 7);
    float4 v = *(const float4*)(whh + (size_t)row * 512 + c4);
    wl[r * 516 + c4 + 0] = v.x; wl[r * 516 + c4 + 1] = v.y;
    wl[r * 516 + c4 + 2] = v.z; wl[r * 516 + c4 + 3] = v.w;
  }
  if (tid < 24) {
    bl[tid] = bhh[(tid >> 3) * 512 + j0 + (tid & 7)];
    if (!L1) bi[tid] = sbih[(tid >> 3) * 512 + j0 + (tid & 7)];
  }
  int part = tid & 7, rr = tid >> 3;

  if (L1) {
    for (int t = 0; t < 512; ++t) {
      float i_r = 0.f, i_z = 0.f, i_n = 0.f;
      if (tid < 16) {   // issue gi loads early; consumed at gate stage
        int b = tid >> 3, jl = tid & 7;
        const float* girow = gi + (size_t)(b * 512 + t) * 1536 + j0 + jl;
        i_r = girow[0]; i_z = girow[512]; i_n = girow[1024];
      }
      if (t > 0) wait_flags(flagsA, (unsigned)t, tid);            // self: h_f(t-1) visible
      if (t >= 4) wait_flags(flagsB, (unsigned)(t - 3), tid);     // ring slot free
      __syncthreads();
      if (t == 0) {
        const unsigned long long* h0q = (const unsigned long long*)h0f;
        hlq[tid] = h0q[tid]; hlq[256 + tid] = h0q[256 + tid];
      } else {
        int boff = ((t - 1) & 3) * 512;
        hlq[tid] = __hip_atomic_load(ringq + boff + tid, __ATOMIC_RELAXED, __HIP_MEMORY_SCOPE_AGENT);
        hlq[256 + tid] = __hip_atomic_load(ringq + boff + 256 + tid, __ATOMIC_RELAXED, __HIP_MEMORY_SCOPE_AGENT);
      }
      __syncthreads();
      if (rr < 24) {
        const float* wr = wl + rr * 516;
        float a0 = 0.f, a1 = 0.f;
        #pragma unroll 8
        for (int i = 0; i < 32; ++i) {
          int c = (i << 4) + (part << 1);
          float2 w = *(const float2*)(wr + c);
          float2 ha = *(const float2*)(hl + c);
          float2 hb = *(const float2*)(hl + 512 + c);
          a0 += w.x * ha.x + w.y * ha.y;
          a1 += w.x * hb.x + w.y * hb.y;
        }
        a0 += __shfl_xor(a0, 1); a0 += __shfl_xor(a0, 2); a0 += __shfl_xor(a0, 4);
        a1 += __shfl_xor(a1, 1); a1 += __shfl_xor(a1, 2); a1 += __shfl_xor(a1, 4);
        if (part == 0) { P[rr] = a0; P[24 + rr] = a1; }
      }
      __syncthreads();
      if (tid < 16) {
        int b = tid >> 3, jl = tid & 7, j = j0 + jl;
        float gh_r = P[b * 24 + jl] + bl[jl];
        float gh_z = P[b * 24 + 8 + jl] + bl[8 + jl];
        float gh_n = P[b * 24 + 16 + jl] + bl[16 + jl];
        float hold = hl[b * 512 + j];
        float rg = 1.0f / (1.0f + __expf(-(i_r + gh_r)));
        float zg = 1.0f / (1.0f + __expf(-(i_z + gh_z)));
        float ng = tanhf(i_n + rg * gh_n);
        float hnew = (1.0f - zg) * ng + zg * hold;
        __hip_atomic_store(ring + (size_t)(t & 3) * 1024 + b * 512 + j, hnew,
                           __ATOMIC_RELAXED, __HIP_MEMORY_SCOPE_AGENT);
        pf_out[(size_t)(b * 512 + t) * 2048 + j] = hnew;
        if (t == 511) hfT[b * 512 + j] = hnew;
      }
      __syncthreads();   // vmcnt drained -> h stores complete before flag post
      if (tid == 0) post_flag(flagsA, wg, (unsigned)(t + 1));
    }
  } else {
    // preload slow_wih rows into registers (interleaved chunks)
    float4 wi[16];
    if (rr < 24) {
      int wrow = (rr >> 3) * 512 + j0 + (rr & 7);
      const float* wp = swih + (size_t)wrow * 512;
      #pragma unroll
      for (int i = 0; i < 16; ++i) wi[i] = *(const float4*)(wp + (i << 5) + (part << 2));
    }
    for (int t2 = 0; t2 < 512; ++t2) {
      wait_flags(flagsA, (unsigned)(t2 + 1), tid);                // p_f(t2) ready
      if (t2 > 0) wait_flags(flagsB, (unsigned)t2, tid);          // self: h_s(t2-1) visible
      __syncthreads();
      if (t2 == 0) {
        const unsigned long long* h0q = (const unsigned long long*)h0s;
        hlq[tid] = h0q[tid]; hlq[256 + tid] = h0q[256 + tid];
      } else {
        int boff = ((t2 - 1) & 1) * 512;
        hlq[tid] = __hip_atomic_load(hsq + boff + tid, __ATOMIC_RELAXED, __HIP_MEMORY_SCOPE_AGENT);
        hlq[256 + tid] = __hip_atomic_load(hsq + boff + 256 + tid, __ATOMIC_RELAXED, __HIP_MEMORY_SCOPE_AGENT);
      }
      {
        int foff = (t2 & 3) * 512;
        hfq[tid] = __hip_atomic_load(ringq + foff + tid, __ATOMIC_RELAXED, __HIP_MEMORY_SCOPE_AGENT);
        hfq[256 + tid] = __hip_atomic_load(ringq + foff + 256 + tid, __ATOMIC_RELAXED, __HIP_MEMORY_SCOPE_AGENT);
      }
      __syncthreads();
      if (rr < 24) {
        // gh = whh (LDS) . h_s
        const float* wr = wl + rr * 516;
        float a0 = 0.f, a1 = 0.f;
        #pragma unroll 8
        for (int i = 0; i < 32; ++i) {
          int c = (i << 4) + (part << 1);
          float2 w = *(const float2*)(wr + c);
          float2 ha = *(const float2*)(hl + c);
          float2 hb = *(const float2*)(hl + 512 + c);
          a0 += w.x * ha.x + w.y * ha.y;
          a1 += w.x * hb.x + w.y * hb.y;
        }
        a0 += __shfl_xor(a0, 1); a0 += __shfl_xor(a0, 2); a0 += __shfl_xor(a0, 4);
        a1 += __shfl_xor(a1, 1); a1 += __shfl_xor(a1, 2); a1 += __shfl_xor(a1, 4);
        if (part == 0) { P[rr] = a0; P[24 + rr] = a1; }
        // gi = swih (regs) . p_f  — conflict-free interleaved fragments
        float b0 = 0.f, b1 = 0.f;
        #pragma unroll
        for (int i = 0; i < 16; ++i) {
          int c = (i << 5) + (part << 2);
          float4 c0 = *(const float4*)(hf + c);
          float4 c1 = *(const float4*)(hf + 512 + c);
          b0 += wi[i].x * c0.x + wi[i].y * c0.y + wi[i].z * c0.z + wi[i].w * c0.w;
          b1 += wi[i].x * c1.x + wi[i].y * c1.y + wi[i].z * c1.z + wi[i].w * c1.w;
        }
        b0 += __shfl_xor(b0, 1); b0 += __shfl_xor(b0, 2); b0 += __shfl_xor(b0, 4);
        b1 += __shfl_xor(b1, 1); b1 += __shfl_xor(b1, 2); b1 += __shfl_xor(b1, 4);
        if (part == 0) { Q[rr] = b0; Q[24 + rr] = b1; }
      }
      __syncthreads();
      if (tid < 16) {
        int b = tid >> 3, jl = tid & 7, j = j0 + jl;
        float i_r = Q[b * 24 + jl] + bi[jl];
        float i_z = Q[b * 24 + 8 + jl] + bi[8 + jl];
        float i_n = Q[b * 24 + 16 + jl] + bi[16 + jl];
        float gh_r = P[b * 24 + jl] + bl[jl];
        float gh_z = P[b * 24 + 8 + jl] + bl[8 + jl];
        float gh_n = P[b * 24 + 16 + jl] + bl[16 + jl];
        float hold = hl[b * 512 + j];
        float rg = 1.0f / (1.0f + __expf(-(i_r + gh_r)));
        float zg = 1.0f / (1.0f + __expf(-(i_z + gh_z)));
        float ng = tanhf(i_n + rg * gh_n);
        float hnew = (1.0f - zg) * ng + zg * hold;
        __hip_atomic_store(hsbuf + (size_t)(t2 & 1) * 1024 + b * 512 + j, hnew,
                           __ATOMIC_RELAXED, __HIP_MEMORY_SCOPE_AGENT);
        ps_out[(size_t)(b * 512 + t2) * 512 + j] = hnew;
        if (t2 == 511) hsT[b * 512 + j] = hnew;
      }
      __syncthreads();   // vmcnt drained -> h_s stores complete before flag post
      if (tid == 0) post_flag(flagsB, wg - 64, (unsigned)(t2 + 1));
    }
  }
}

// ---------- row reductions ----------
__global__ __launch_bounds__(256) void rowsum_kernel(const float* __restrict__ S,
                                                     float* __restrict__ den) {
  int m = blockIdx.x, tid = threadIdx.x;
  float s = S[(size_t)m * 512 + tid] + S[(size_t)m * 512 + 256 + tid];
  #pragma unroll
  for (int off = 32; off > 0; off >>= 1) s += __shfl_down(s, off);
  __shared__ float r4[4];
  if ((tid & 63) == 0) r4[tid >> 6] = s;
  __syncthreads();
  if (tid == 0) den[m] = r4[0] + r4[1] + r4[2] + r4[3];
}

__global__ __launch_bounds__(256) void softmax_kernel(float* __restrict__ a) {
  int m = blockIdx.x, tid = threadIdx.x;
  float v = a[(size_t)m * 256 + tid];
  float mx = v;
  #pragma unroll
  for (int off = 32; off > 0; off >>= 1) mx = fmaxf(mx, __shfl_down(mx, off));
  __shared__ float r4[4];
  __shared__ float s4[4];
  if ((tid & 63) == 0) r4[tid >> 6] = mx;
  __syncthreads();
  mx = fmaxf(fmaxf(r4[0], r4[1]), fmaxf(r4[2], r4[3]));
  float e = __expf(v - mx);
  float s = e;
  #pragma unroll
  for (int off = 32; off > 0; off >>= 1) s += __shfl_down(s, off);
  if ((tid & 63) == 0) s4[tid >> 6] = s;
  __syncthreads();
  s = s4[0] + s4[1] + s4[2] + s4[3];
  a[(size_t)m * 256 + tid] = e / s;
}

__global__ __launch_bounds__(256) void ln_kernel(
    const float* __restrict__ src, float* __restrict__ dst, int ldd, int dcoff,
    const float* __restrict__ gv, const float* __restrict__ bv, int tanhFirst) {
  int m = blockIdx.x, tid = threadIdx.x;
  float x0 = src[(size_t)m * 512 + tid];
  float x1 = src[(size_t)m * 512 + 256 + tid];
  if (tanhFirst) { x0 = tanhf(x0); x1 = tanhf(x1); }
  float s = x0 + x1, ss = x0 * x0 + x1 * x1;
  #pragma unroll
  for (int off = 32; off > 0; off >>= 1) { s += __shfl_down(s, off); ss += __shfl_down(ss, off); }
  __shared__ float rs[4], rss[4];
  if ((tid & 63) == 0) { rs[tid >> 6] = s; rss[tid >> 6] = ss; }
  __syncthreads();
  float st = rs[0] + rs[1] + rs[2] + rs[3];
  float sst = rss[0] + rss[1] + rss[2] + rss[3];
  float mean = st * (1.0f / 512.0f);
  float var = sst * (1.0f / 512.0f) - mean * mean;
  float inv = rsqrtf(var + 1e-5f);
  float y0 = (x0 - mean) * inv * gv[tid] + bv[tid];
  float y1 = (x1 - mean) * inv * gv[256 + tid] + bv[256 + tid];
  if (!tanhFirst) { y0 = tanhf(y0); y1 = tanhf(y1); }
  dst[(size_t)m * ldd + dcoff + tid] = y0;
  dst[(size_t)m * ldd + dcoff + 256 + tid] = y1;
}

__global__ __launch_bounds__(256) void swnorm_kernel(const float* __restrict__ soma,
                                                     float* __restrict__ sw) {
  int r = blockIdx.x, tid = threadIdx.x;
  float x0 = soma[(size_t)r * 512 + tid];
  float x1 = soma[(size_t)r * 512 + 256 + tid];
  float ss = x0 * x0 + x1 * x1;
  #pragma unroll
  for (int off = 32; off > 0; off >>= 1) ss += __shfl_down(ss, off);
  __shared__ float r4[4];
  if ((tid & 63) == 0) r4[tid >> 6] = ss;
  __syncthreads();
  float norm = sqrtf(r4[0] + r4[1] + r4[2] + r4[3]);
  norm = fmaxf(norm, 1e-12f);
  float inv = 1.0f / norm;
  sw[(size_t)r * 512 + tid] = x0 * inv;
  sw[(size_t)r * 512 + 256 + tid] = x1 * inv;
}

// ---------- host ----------
extern "C" void kernel_launch(void* const* d_in, const int* in_sizes, int n_in,
                              void* d_out, int out_size, void* d_ws, size_t ws_size,
                              hipStream_t stream) {
  (void)in_sizes; (void)n_in; (void)out_size; (void)ws_size;
  float* W = (float*)d_ws;
  float* outf = (float*)d_out;
  // out layout (floats): logits[262144] | thought[524288] | hf1[1024] | hs1[1024]
  const int* x = (const int*)d_in[0];
  const float* soma = (const float*)d_in[3];

  hipMemsetAsync((char*)d_ws + (size_t)OFF_FLAGS * 4, 0, 16384, stream);

  embed_kernel<<<2048, 256, 0, stream>>>(soma, x, W + OFF_SIN);

  // gi_f = s_in @ fast_wih^T + fast_bih
  gemm<<<dim3(24, 16), 256, 0, stream>>>(W + OFF_SIN, 512, (const float*)d_in[4], 512,
      W + OFF_GI, 1536, 0, 512, (const float*)d_in[6], nullptr, 1.f, 0, 0);

  // fused GRU1+GRU2 -> p_f (COMB cols [0,512)), p_s (PS), hf1/hs1 -> out
  gru2_kernel<<<128, 256, 0, stream>>>(W + OFF_GI,
      (const float*)d_in[5], (const float*)d_in[7], (const float*)d_in[1],
      (const float*)d_in[8], (const float*)d_in[10],
      (const float*)d_in[9], (const float*)d_in[11], (const float*)d_in[2],
      W + OFF_COMB, W + OFF_PS, outf + 786432, outf + 787456,
      W + OFF_RING, W + OFF_HSB,
      (unsigned*)(W + OFF_FLAGS), (unsigned*)(W + OFF_FLAGS) + 64 * FLAG_STRIDE);

  // qkv = p_s @ qkv_w^T + b ; elu+1 on q,k
  gemm<<<dim3(24, 16), 256, 0, stream>>>(W + OFF_PS, 512, (const float*)d_in[12], 512,
      W + OFF_QKV, 1536, 0, 512, (const float*)d_in[13], nullptr, 1.f, F_ELUQK, 0);

  // scores = causal(q k^T) per batch
  gemm<<<dim3(8, 16), 256, 0, stream>>>(W + OFF_QKV, 1536, W + OFF_QKV + 512, 1536,
      W + OFF_SCORES, 512, 0, 512, nullptr, nullptr, 1.f, F_CAUSAL, 512);

  rowsum_kernel<<<1024, 256, 0, stream>>>(W + OFF_SCORES, W + OFF_DEN);

  // l_mem = (scores @ v) / (den + 1e-6) -> combined cols [1024,1536)
  gemm<<<dim3(8, 16), 256, 0, stream>>>(W + OFF_SCORES, 512, W + OFF_QKV + 1024, 1536,
      W + OFF_COMB, 2048, 1024, 512, nullptr, W + OFF_DEN, 1.f, F_NN | F_DIV, 512);

  // intent = tanh(LN(p_s @ gate_w^T + gate_b)) -> combined cols [512,1024)
  gemm<<<dim3(8, 16), 256, 0, stream>>>(W + OFF_PS, 512, (const float*)d_in[14], 512,
      W + OFF_TMP, 512, 0, 512, (const float*)d_in[15], nullptr, 1.f, 0, 0);
  ln_kernel<<<1024, 256, 0, stream>>>(W + OFF_TMP, W + OFF_COMB, 2048, 512,
      (const float*)d_in[16], (const float*)d_in[17], 0);

  // hippocampus -> combined cols [1536,2048)
  gemm<<<dim3(8, 16), 256, 0, stream>>>(W + OFF_PS, 512, (const float*)d_in[19], 512,
      W + OFF_TMP, 512, 0, 512, (const float*)d_in[20], nullptr, 1.f, 0, 0);
  gemm<<<dim3(4, 16), 256, 0, stream>>>(W + OFF_TMP, 512, (const float*)d_in[18], 512,
      W + OFF_ATTN, 256, 0, 512, nullptr, nullptr, 0.04419417382415922f, F_SCALE, 0);
  softmax_kernel<<<1024, 256, 0, stream>>>(W + OFF_ATTN);
  gemm<<<dim3(8, 16), 256, 0, stream>>>(W + OFF_ATTN, 256, (const float*)d_in[18], 512,
      W + OFF_COMB, 2048, 1536, 256, nullptr, nullptr, 1.f, F_NN, 0);

  // axon + LN -> thought directly into out (fp32)
  gemm<<<dim3(8, 16), 256, 0, stream>>>(W + OFF_COMB, 2048, (const float*)d_in[21], 2048,
      W + OFF_TMP, 512, 0, 2048, (const float*)d_in[22], nullptr, 1.f, 0, 0);
  ln_kernel<<<1024, 256, 0, stream>>>(W + OFF_TMP, outf + 262144, 512, 0,
      (const float*)d_in[23], (const float*)d_in[24], 1);

  // logits = (thought @ sw^T) * 16 -> out (fp32)
  swnorm_kernel<<<256, 256, 0, stream>>>(soma, W + OFF_SW);
  gemm<<<dim3(4, 16), 256, 0, stream>>>(outf + 262144, 512, W + OFF_SW, 512,
      outf, 256, 0, 512, nullptr, nullptr, 16.f, F_SCALE, 0);
}